// Round 2
// baseline (309.102 us; speedup 1.0000x reference)
//
#include <hip/hip_runtime.h>
#include <hip/hip_bf16.h>
#include <cstdint>

// Problem constants
#define Bn   1024
#define Tn   128
#define En   300
#define Hn   100
#define Vn   50000
#define G4n  400   // 4*H
#define MPn  50048 // V padded to mult of 64
#define NPn  448   // 4H padded to mult of 16 (28 n-tiles)
// gate-column PERMUTATION: jp = 4*u + q  <->  j = q*100 + u  (q = gate i,f,g,o)

typedef __bf16 bf16x8 __attribute__((ext_vector_type(8)));
typedef _Float16 half8 __attribute__((ext_vector_type(8)));
typedef _Float16 half2v __attribute__((ext_vector_type(2)));
typedef float  f32x4  __attribute__((ext_vector_type(4)));

// workspace byte offsets (total 72,764,608 B; <= 94 MB known-good)
#define OFF_TABLE  0ull         // f16 [Vn][448] permuted cols   44,800,000
#define OFF_OH16   44800000ull  // f16 [Bn][Tn][Hn]              26,214,400
#define OFF_WFRAG  71014400ull  // uint4 [28*4*64] W_hh B-frags     114,688
#define OFF_WFRAGB 71129088ull  // uint4 [10*28*64] W_ih B-frags    286,720
#define OFF_LLWT   71415808ull  // f32 [300][100] llW transposed    120,000
#define OFF_LV     71535808ull  // f32 [Bn][Hn]                     409,600
#define OFF_PN     71945408ull  // f32 [Bn][Hn]                     409,600
#define OFF_NEG    72355008ull  // f32 [Bn][Hn]                     409,600

__device__ __forceinline__ float sigf(float x) { return 1.0f / (1.0f + __expf(-x)); }
__device__ __forceinline__ float tanhfast(float x) { return 1.0f - 2.0f / (__expf(2.0f * x) + 1.0f); }

// LDS-only barrier: drain lgkmcnt but leave vmcnt free-running so the table
// gather prefetch + oh16 stores stay in flight across the barrier.
#define BAR_LDS() do {                                         \
    asm volatile("s_waitcnt lgkmcnt(0)" ::: "memory");          \
    __builtin_amdgcn_s_barrier();                               \
    asm volatile("" ::: "memory");                              \
} while (0)

// VALU-pipe lane shift-down by N within each 16-lane row (0-fill past row
// end): DPP row_shl:N — lane i reads lane i+N. No lgkmcnt involvement.
#define DPP_ADD_SHL(v, N) do {                                                     \
    int _s = __builtin_amdgcn_update_dpp(0, __builtin_bit_cast(int, (v)),          \
                                         0x100 | (N), 0xF, 0xF, true);             \
    (v) += __builtin_bit_cast(float, _s);                                          \
} while (0)

// -------- K0: W_hh -> f16 B-frags; W_ih -> bf16 B-frags; llW -> transposed ---
__global__ void k_prep(const float* __restrict__ W_ih, const float* __restrict__ W_hh,
                       const float* __restrict__ llW,
                       uint4* __restrict__ wfrag, uint4* __restrict__ wfragB,
                       float* __restrict__ llwt) {
    int idx = blockIdx.x * 256 + threadIdx.x;
    if (idx < 28 * 4 * 64) {  // W_hh frag: lane holds B[n=nt*16+(l&15)][k=kc*32+(l>>4)*8+j]
        int lane = idx & 63, tk = idx >> 6;
        int nt = tk >> 2, kc = tk & 3;
        int n = nt * 16 + (lane & 15);
        int k0 = kc * 32 + (lane >> 4) * 8;
        int q = n & 3, u = n >> 2;
        union { _Float16 h[8]; uint4 v; } pk;
#pragma unroll
        for (int j = 0; j < 8; j++) {
            int k = k0 + j;
            pk.h[j] = (_Float16)((u < Hn && k < Hn) ? W_hh[(size_t)(q * Hn + u) * Hn + k] : 0.0f);
        }
        wfrag[idx] = pk.v;
    }
    if (idx < 10 * 28 * 64) {  // W_ih frag (bf16): kc-major
        int lane = idx & 63, tk = idx >> 6;
        int kc = tk / 28, nsg = tk - kc * 28;
        int n = nsg * 16 + (lane & 15);
        int k0 = kc * 32 + (lane >> 4) * 8;
        int q = n & 3, u = n >> 2;
        union { __bf16 h[8]; uint4 v; } pk;
#pragma unroll
        for (int j = 0; j < 8; j++) {
            int k = k0 + j;
            pk.h[j] = (__bf16)((u < Hn && k < En) ? W_ih[(size_t)(q * Hn + u) * En + k] : 0.0f);
        }
        wfragB[idx] = pk.v;
    }
    if (idx < En * Hn) {  // llwt[k][h] = llW[h][k]
        int k = idx / Hn, h = idx - k * Hn;
        llwt[idx] = llW[(size_t)h * En + k];
    }
}

// -------- K1: table = emb @ W_ih^T + b (permuted cols, f16 out) --------------
__global__ __launch_bounds__(256, 2) void k_table(
    const float* __restrict__ emb, const uint4* __restrict__ wfragB,
    const float* __restrict__ b_ih, const float* __restrict__ b_hh,
    _Float16* __restrict__ table) {
    __shared__ __bf16 a_sh[64][328];   // 41,984 B (stride 328: rows offset 4 banks)
    const int tid = threadIdx.x;
    const int mt = blockIdx.x >> 1, nh = blockIdx.x & 1;

    // stage A: 64 rows x 320 cols (zeros past 300)
#pragma unroll
    for (int it = 0; it < 5; it++) {
        int x = it * 256 + tid;            // 0..1279
        int row = x / 20, seg = x - row * 20;
        int gr = mt * 64 + row;
        const float* ar = emb + (size_t)(gr < Vn ? gr : Vn - 1) * En;
        int c0 = seg * 16;
        union { __bf16 h[16]; bf16x8 v[2]; } pk;
#pragma unroll
        for (int g = 0; g < 4; g++) {
            int c = c0 + g * 4;
            if (c + 4 <= En) {
                float4 f = *(const float4*)(ar + c);
                pk.h[g * 4 + 0] = (__bf16)f.x; pk.h[g * 4 + 1] = (__bf16)f.y;
                pk.h[g * 4 + 2] = (__bf16)f.z; pk.h[g * 4 + 3] = (__bf16)f.w;
            } else {
                pk.h[g * 4 + 0] = (__bf16)0.f; pk.h[g * 4 + 1] = (__bf16)0.f;
                pk.h[g * 4 + 2] = (__bf16)0.f; pk.h[g * 4 + 3] = (__bf16)0.f;
            }
        }
        *(bf16x8*)&a_sh[row][c0] = pk.v[0];
        *(bf16x8*)&a_sh[row][c0 + 8] = pk.v[1];
    }
    __syncthreads();

    const int wv = tid >> 6, l = tid & 63;
    const int c16 = l & 15, quad = l >> 4;
    f32x4 acc[14];
#pragma unroll
    for (int i = 0; i < 14; i++) acc[i] = (f32x4){0.f, 0.f, 0.f, 0.f};

    uint4 bcur[14];
#pragma unroll
    for (int ns = 0; ns < 14; ns++) bcur[ns] = wfragB[((0 * 28 + nh * 14 + ns) << 6) + l];

    for (int kc = 0; kc < 10; kc++) {
        uint4 bnxt[14];
        if (kc < 9) {
#pragma unroll
            for (int ns = 0; ns < 14; ns++) bnxt[ns] = wfragB[(((kc + 1) * 28 + nh * 14 + ns) << 6) + l];
        }
        bf16x8 af = *(const bf16x8*)&a_sh[wv * 16 + c16][kc * 32 + quad * 8];
#pragma unroll
        for (int ns = 0; ns < 14; ns++)
            acc[ns] = __builtin_amdgcn_mfma_f32_16x16x32_bf16(af, __builtin_bit_cast(bf16x8, bcur[ns]), acc[ns], 0, 0, 0);
        if (kc < 9) {
#pragma unroll
            for (int ns = 0; ns < 14; ns++) bcur[ns] = bnxt[ns];
        }
    }
    // epilogue: C/D row = quad*4+r, col = c16
#pragma unroll
    for (int ns = 0; ns < 14; ns++) {
        int n = (nh * 14 + ns) * 16 + c16;
        int q = n & 3, u = n >> 2;
        if (u < Hn) {
            int j = q * Hn + u;
            float bias = b_ih[j] + b_hh[j];
#pragma unroll
            for (int r = 0; r < 4; r++) {
                int m = mt * 64 + wv * 16 + quad * 4 + r;
                if (m < Vn) table[(size_t)m * NPn + n] = (_Float16)(acc[ns][r] + bias);
            }
        }
    }
}

// -------- K2: label_vec = emb[lid] @ ll_W^T + ll_b (2-way K split) -----------
__global__ void k_label(const int* __restrict__ lwid, const float* __restrict__ emb,
                        const float* __restrict__ llwt, const float* __restrict__ llb,
                        float* __restrict__ lv) {
    __shared__ float er[En];
    __shared__ float part[Hn];
    int b = blockIdx.x;
    int lid = lwid[b];
    for (int k = threadIdx.x; k < En; k += 256) er[k] = emb[(size_t)lid * En + k];
    __syncthreads();
    int h = threadIdx.x & 127, half = threadIdx.x >> 7;
    float acc = 0.f;
    if (h < Hn) {
        int k0 = half * 150, k1 = k0 + 150;
        for (int k = k0; k < k1; k++) acc += er[k] * llwt[k * Hn + h];
        if (half == 1) part[h] = acc;
    }
    __syncthreads();
    if (h < Hn && half == 0) lv[(size_t)b * Hn + h] = acc + part[h] + llb[h];
}

// -------- K3: fused LSTM, 2 batch/block, MFMA f16, ONE barrier/step ----------
// Wave w owns u in [28w, 28w+28) x mb in {0,1} (lane = 2*u_loc + mb).
// Chain-shortening vs prior rev:
//  * score reduce = 3 DPP row_shl adds (VALU pipe, no lgkm) -> 16 partials
//    written to spw[2][T][16]; the reduce of step t-1 is DEFERRED into step
//    t's MFMA phase (off the barrier path). Epilogue top-k sums 16 partials.
//  * xq table gather prefetched TWO steps ahead (L3 latency ~900cy fully
//    hidden under one full step).
//  * lt hoisted to a register (no per-step ds_read).
__global__ __launch_bounds__(256, 2) void k_lstm(
    const int* __restrict__ word_id, const int* __restrict__ sen_len,
    const _Float16* __restrict__ table, const uint4* __restrict__ wfrag,
    const float* __restrict__ lv, const float* __restrict__ linW,
    const float* __restrict__ linb, _Float16* __restrict__ oh16,
    float* __restrict__ per_neg, float* __restrict__ d_out) {
    __shared__ float    gbufs[4][280];     // per wave [2 mb][140] stride-5
    __shared__ _Float16 h_cur[2][2][136];  // [parity][mb][136], cols>=100 zero
    __shared__ float    spw[2][Tn][16];    // per-(wave,row) score partials
    __shared__ int      widc[2][Tn];
    __shared__ float    pos_sh[2][Hn];
    __shared__ float    lasth_sh[2][Hn];
    __shared__ float    tk_val[2][4];
    __shared__ int      tk_idx[2][4];

    const int tid = threadIdx.x;
    const int w = tid >> 6, l = tid & 63;
    const int c16 = l & 15, quad = l >> 4;
    const int b0 = blockIdx.x * 2;

    // init
    for (int i = tid; i < 272; i += 256) ((uint32_t*)h_cur)[i] = 0u;  // both parities + pads
    { int imb = tid >> 7, it = tid & 127; widc[imb][it] = word_id[(b0 + imb) * Tn + it]; }

    // persistent W_hh B-fragments
    half8 bfr[7][4];
#pragma unroll
    for (int n7 = 0; n7 < 7; n7++)
#pragma unroll
        for (int kc = 0; kc < 4; kc++)
            bfr[n7][kc] = __builtin_bit_cast(half8, wfrag[((w * 7 + n7) * 4 + kc) * 64 + l]);

    // lane work identity
    const int u_loc = l >> 1, mb = l & 1;
    const int u = w * 28 + u_loc;
    const bool act = (l < 56) && (u < Hn);
    const int myslen = act ? sen_len[b0 + mb] : 0;
    const float lt_reg = act ? lv[(size_t)(b0 + mb) * Hn + u] : 0.f;
    float* gb = &gbufs[w][0];

    __syncthreads();

    uint2 xq = {0, 0}, xq1 = {0, 0};
    if (act) {
        xq  = *(const uint2*)(table + (size_t)widc[mb][0] * NPn + u * 4);
        xq1 = *(const uint2*)(table + (size_t)widc[mb][1] * NPn + u * 4);
    }

    float c_reg = 0.f, sumh = 0.f, lasth = 0.f;
    float p_carry = 0.f;                    // score partial of step t-1
    _Float16* ohb_w = oh16 + (size_t)(b0 + mb) * Tn * Hn;

    for (int t = 0; t < Tn; t++) {
        // ---- MFMA: gates = h . W_hh^T (A from parity t&1)
        const _Float16* hp = &h_cur[t & 1][0][0];
        f32x4 acc[7];
#pragma unroll
        for (int n7 = 0; n7 < 7; n7++) acc[n7] = (f32x4){0.f, 0.f, 0.f, 0.f};
#pragma unroll
        for (int kc = 0; kc < 4; kc++) {
            half8 af = *(const half8*)(hp + (c16 & 1) * 136 + kc * 32 + quad * 8);
#pragma unroll
            for (int n7 = 0; n7 < 7; n7++)
                acc[n7] = __builtin_amdgcn_mfma_f32_16x16x32_f16(af, bfr[n7][kc], acc[n7], 0, 0, 0);
        }
        // ---- deferred score reduce for step t-1 (VALU DPP; overlaps MFMA)
        {
            float pr = p_carry;
            DPP_ADD_SHL(pr, 2);
            DPP_ADD_SHL(pr, 4);
            DPP_ADD_SHL(pr, 8);
            // lanes with (l&15)<2 hold row partials (parity = mb)
            if ((l & 15) < 2 && t > 0) spw[l & 1][t - 1][w * 4 + quad] = pr;
        }
        // ---- wave-local gate stage (C rows 0,1 live in quad 0)
        if (l < 16) {
#pragma unroll
            for (int n7 = 0; n7 < 7; n7++) {
                int nl = n7 * 16 + l;
                int adr = (nl >> 2) * 5 + (nl & 3);
                gb[adr] = acc[n7][0];
                gb[140 + adr] = acc[n7][1];
            }
        }
        // wave-synchronous: lgkmcnt ordering within wave, no barrier
        float p = 0.f;
        if (act) {
            int base = mb * 140 + u_loc * 5;
            half2v x01 = __builtin_bit_cast(half2v, xq.x);
            half2v x23 = __builtin_bit_cast(half2v, xq.y);
            float gi = gb[base] + (float)x01.x;
            float gf = gb[base + 1] + (float)x01.y;
            float gg = gb[base + 2] + (float)x23.x;
            float go = gb[base + 3] + (float)x23.y;
            float c = sigf(gf) * c_reg + sigf(gi) * tanhfast(gg);
            c_reg = c;
            float hh = sigf(go) * tanhfast(c);
            h_cur[(t + 1) & 1][mb][u] = (_Float16)hh;
            ohb_w[t * Hn + u] = (_Float16)hh;
            if (t < myslen) sumh += hh;
            if (t == myslen - 1) lasth = hh;
            p = hh * lt_reg;
            int tn2 = (t + 2 < Tn) ? t + 2 : Tn - 1;
            xq = xq1;
            xq1 = *(const uint2*)(table + (size_t)widc[mb][tn2] * NPn + u * 4);
        }
        p_carry = p;
        BAR_LDS();  // h(t+1) + spw visible to all waves; vmcnt stays in flight
    }
    // final deferred reduce for t = Tn-1
    {
        float pr = p_carry;
        DPP_ADD_SHL(pr, 2);
        DPP_ADD_SHL(pr, 4);
        DPP_ADD_SHL(pr, 8);
        if ((l & 15) < 2) spw[l & 1][Tn - 1][w * 4 + quad] = pr;
    }
    __syncthreads();  // spw complete; drains vmcnt (oh16 stores) before re-read
    // ---- top-4: wave 0 -> mb 0, wave 1 -> mb 1; tie-break smaller index
    if (w < 2) {
        int kmb = w, lane = l;
        int sl = sen_len[b0 + kmb];
        const float* s16a = &spw[kmb][lane][0];
        const float* s16b = &spw[kmb][lane + 64][0];
        float4 a0 = *(const float4*)(s16a + 0), a1 = *(const float4*)(s16a + 4);
        float4 a2 = *(const float4*)(s16a + 8), a3 = *(const float4*)(s16a + 12);
        float4 b0v = *(const float4*)(s16b + 0), b1v = *(const float4*)(s16b + 4);
        float4 b2v = *(const float4*)(s16b + 8), b3v = *(const float4*)(s16b + 12);
        float sa = (a0.x + a0.y + a0.z + a0.w) + (a1.x + a1.y + a1.z + a1.w)
                 + (a2.x + a2.y + a2.z + a2.w) + (a3.x + a3.y + a3.z + a3.w);
        float sb = (b0v.x + b0v.y + b0v.z + b0v.w) + (b1v.x + b1v.y + b1v.z + b1v.w)
                 + (b2v.x + b2v.y + b2v.z + b2v.w) + (b3v.x + b3v.y + b3v.z + b3v.w);
        float s0 = (lane < sl) ? sa : -1e30f;
        float s1 = (lane + 64 < sl) ? sb : -1e30f;
        bool tk0 = false, tk1 = false;
#pragma unroll
        for (int p4 = 0; p4 < 4; p4++) {
            float v = tk0 ? -1e30f : s0;
            int ix = lane;
            float v1 = tk1 ? -1e30f : s1;
            if (v1 > v) { v = v1; ix = lane + 64; }
            for (int off = 32; off; off >>= 1) {
                float ov = __shfl_down(v, off, 64);
                int oi = __shfl_down(ix, off, 64);
                if (ov > v || (ov == v && oi < ix)) { v = ov; ix = oi; }
            }
            v = __shfl(v, 0, 64);
            ix = __shfl(ix, 0, 64);
            if (lane == 0) { tk_val[kmb][p4] = v; tk_idx[kmb][p4] = ix; }
            if (ix == lane) tk0 = true;
            if (ix == lane + 64) tk1 = true;
        }
    }
    __syncthreads();
    // ---- pos / per_neg / lasth (lane ownership)
    if (act) {
        float pos = 0.f, nsum = sumh;
#pragma unroll
        for (int p4 = 0; p4 < 4; p4++) {
            int ix = tk_idx[mb][p4];
            float r = (float)ohb_w[ix * Hn + u];
            pos += tk_val[mb][p4] * r;
            nsum -= r;
        }
        pos_sh[mb][u] = pos;
        lasth_sh[mb][u] = lasth;
        per_neg[(size_t)(b0 + mb) * Hn + u] = nsum;
    }
    __syncthreads();
    // ---- projections: out_f = lin(lasth), l_rep = lin(pos)
    if (tid < 24) {
        int which = tid / 12, r = tid - which * 12;
        int pmb = r / 6, o = r - pmb * 6;
        const float* src = which ? &pos_sh[pmb][0] : &lasth_sh[pmb][0];
        float acc2 = linb[o];
        for (int uu = 0; uu < Hn; uu++) acc2 += src[uu] * linW[o * Hn + uu];
        d_out[(which ? (Bn * 6) : 0) + (b0 + pmb) * 6 + o] = acc2;
    }
}

// -------- K4: batch cumsum of per_neg (wave-shuffle scan, 2 barriers) --------
__global__ __launch_bounds__(1024) void k_scan(const float* __restrict__ pn, float* __restrict__ neg) {
    __shared__ float wsum[16];
    __shared__ float wpre[16];
    int u = blockIdx.x, t = threadIdx.x;
    int lane = t & 63, wv = t >> 6;
    float v = pn[(size_t)t * Hn + u];
#pragma unroll
    for (int off = 1; off < 64; off <<= 1) {
        float o = __shfl_up(v, off, 64);
        if (lane >= off) v += o;
    }
    if (lane == 63) wsum[wv] = v;
    __syncthreads();
    if (t < 16) {
        float s = wsum[t];
#pragma unroll
        for (int off = 1; off < 16; off <<= 1) {
            float o = __shfl_up(s, off, 64);
            if (t >= off) s += o;
        }
        wpre[t] = s;
    }
    __syncthreads();
    float pre = wv ? wpre[wv - 1] : 0.f;
    neg[(size_t)t * Hn + u] = v + pre;
}

// -------- K5: r_rep = neg @ lin_W^T + lin_b ----------------------------------
__global__ void k_rrep(const float* __restrict__ neg, const float* __restrict__ linW,
                       const float* __restrict__ linb, float* __restrict__ d_out) {
    int gid = blockIdx.x * 256 + threadIdx.x;
    if (gid < Bn * 6) {
        int b = gid / 6, o = gid - b * 6;
        float acc = linb[o];
        for (int u = 0; u < Hn; u++) acc += neg[(size_t)b * Hn + u] * linW[o * Hn + u];
        d_out[2 * Bn * 6 + gid] = acc;
    }
}

extern "C" void kernel_launch(void* const* d_in, const int* in_sizes, int n_in,
                              void* d_out, int out_size, void* d_ws, size_t ws_size,
                              hipStream_t stream) {
    const int*   word_id = (const int*)d_in[0];
    const int*   sen_len = (const int*)d_in[1];
    const int*   lwid    = (const int*)d_in[2];
    const float* emb     = (const float*)d_in[3];
    const float* W_ih    = (const float*)d_in[4];
    const float* W_hh    = (const float*)d_in[5];
    const float* b_ih    = (const float*)d_in[6];
    const float* b_hh    = (const float*)d_in[7];
    const float* linW    = (const float*)d_in[8];
    const float* linb    = (const float*)d_in[9];
    const float* llW     = (const float*)d_in[10];
    const float* llb     = (const float*)d_in[11];

    char* ws = (char*)d_ws;
    _Float16* table  = (_Float16*)(ws + OFF_TABLE);
    _Float16* oh16   = (_Float16*)(ws + OFF_OH16);
    uint4*    wfrag  = (uint4*)(ws + OFF_WFRAG);
    uint4*    wfragB = (uint4*)(ws + OFF_WFRAGB);
    float*    llwt   = (float*)(ws + OFF_LLWT);
    float*    lvp    = (float*)(ws + OFF_LV);
    float*    pn     = (float*)(ws + OFF_PN);
    float*    neg    = (float*)(ws + OFF_NEG);
    float*    outp   = (float*)d_out;

    k_prep<<<118, 256, 0, stream>>>(W_ih, W_hh, llW, wfrag, wfragB, llwt);
    k_table<<<(MPn / 64) * 2, 256, 0, stream>>>(emb, wfragB, b_ih, b_hh, table);
    k_label<<<Bn, 256, 0, stream>>>(lwid, emb, llwt, llb, lvp);
    k_lstm<<<Bn / 2, 256, 0, stream>>>(word_id, sen_len, table, wfrag, lvp, linW, linb, oh16, pn, outp);
    k_scan<<<Hn, 1024, 0, stream>>>(pn, neg);
    k_rrep<<<(Bn * 6 + 255) / 256, 256, 0, stream>>>(neg, linW, linb, outp);
}

// Round 3
// 307.173 us; speedup vs baseline: 1.0063x; 1.0063x over previous
//
#include <hip/hip_runtime.h>
#include <hip/hip_bf16.h>
#include <cstdint>

// Problem constants
#define Bn   1024
#define Tn   128
#define En   300
#define Hn   100
#define Vn   50000
#define G4n  400   // 4*H
#define MPn  50048 // V padded to mult of 64
#define NPn  448   // 4H padded to mult of 16 (28 n-tiles)
// gate-column PERMUTATION: jp = 4*u + q  <->  j = q*100 + u  (q = gate i,f,g,o)

typedef __bf16 bf16x8 __attribute__((ext_vector_type(8)));
typedef _Float16 half8 __attribute__((ext_vector_type(8)));
typedef _Float16 half2v __attribute__((ext_vector_type(2)));
typedef float  f32x4  __attribute__((ext_vector_type(4)));

// workspace byte offsets (total 72,764,608 B; <= 94 MB known-good)
#define OFF_TABLE  0ull         // f16 [Vn][448] permuted cols   44,800,000
#define OFF_OH16   44800000ull  // f16 [Bn][Tn][Hn]              26,214,400
#define OFF_WFRAG  71014400ull  // uint4 [28*4*64] W_hh B-frags     114,688
#define OFF_WFRAGB 71129088ull  // uint4 [10*28*64] W_ih B-frags    286,720
#define OFF_LLWT   71415808ull  // f32 [300][100] llW transposed    120,000
#define OFF_LV     71535808ull  // f32 [Bn][Hn]                     409,600
#define OFF_PN     71945408ull  // f32 [Bn][Hn]                     409,600
#define OFF_NEG    72355008ull  // f32 [Bn][Hn]                     409,600

__device__ __forceinline__ float sigf(float x) { return 1.0f / (1.0f + __expf(-x)); }
__device__ __forceinline__ float tanhfast(float x) { return 1.0f - 2.0f / (__expf(2.0f * x) + 1.0f); }

// LDS-only barrier: drain lgkmcnt but leave vmcnt free-running so the table
// gather prefetch + oh16 stores stay in flight across the barrier.
#define BAR_LDS() do {                                         \
    asm volatile("s_waitcnt lgkmcnt(0)" ::: "memory");          \
    __builtin_amdgcn_s_barrier();                               \
    asm volatile("" ::: "memory");                              \
} while (0)

// VALU-pipe lane shift-down by N within each 16-lane row (0-fill past row
// end): DPP row_shl:N — lane i reads lane i+N. No lgkmcnt involvement.
#define DPP_ADD_SHL(v, N) do {                                                     \
    int _s = __builtin_amdgcn_update_dpp(0, __builtin_bit_cast(int, (v)),          \
                                         0x100 | (N), 0xF, 0xF, true);             \
    (v) += __builtin_bit_cast(float, _s);                                          \
} while (0)

// -------- K0: W_hh -> f16 B-frags; W_ih -> bf16 B-frags; llW -> transposed ---
__global__ void k_prep(const float* __restrict__ W_ih, const float* __restrict__ W_hh,
                       const float* __restrict__ llW,
                       uint4* __restrict__ wfrag, uint4* __restrict__ wfragB,
                       float* __restrict__ llwt) {
    int idx = blockIdx.x * 256 + threadIdx.x;
    if (idx < 28 * 4 * 64) {  // W_hh frag: lane holds B[n=nt*16+(l&15)][k=kc*32+(l>>4)*8+j]
        int lane = idx & 63, tk = idx >> 6;
        int nt = tk >> 2, kc = tk & 3;
        int n = nt * 16 + (lane & 15);
        int k0 = kc * 32 + (lane >> 4) * 8;
        int q = n & 3, u = n >> 2;
        union { _Float16 h[8]; uint4 v; } pk;
#pragma unroll
        for (int j = 0; j < 8; j++) {
            int k = k0 + j;
            pk.h[j] = (_Float16)((u < Hn && k < Hn) ? W_hh[(size_t)(q * Hn + u) * Hn + k] : 0.0f);
        }
        wfrag[idx] = pk.v;
    }
    if (idx < 10 * 28 * 64) {  // W_ih frag (bf16): kc-major
        int lane = idx & 63, tk = idx >> 6;
        int kc = tk / 28, nsg = tk - kc * 28;
        int n = nsg * 16 + (lane & 15);
        int k0 = kc * 32 + (lane >> 4) * 8;
        int q = n & 3, u = n >> 2;
        union { __bf16 h[8]; uint4 v; } pk;
#pragma unroll
        for (int j = 0; j < 8; j++) {
            int k = k0 + j;
            pk.h[j] = (__bf16)((u < Hn && k < En) ? W_ih[(size_t)(q * Hn + u) * En + k] : 0.0f);
        }
        wfragB[idx] = pk.v;
    }
    if (idx < En * Hn) {  // llwt[k][h] = llW[h][k]
        int k = idx / Hn, h = idx - k * Hn;
        llwt[idx] = llW[(size_t)h * En + k];
    }
}

// -------- K1: table = emb @ W_ih^T + b (permuted cols, f16 out) --------------
__global__ __launch_bounds__(256, 2) void k_table(
    const float* __restrict__ emb, const uint4* __restrict__ wfragB,
    const float* __restrict__ b_ih, const float* __restrict__ b_hh,
    _Float16* __restrict__ table) {
    __shared__ __bf16 a_sh[64][328];   // 41,984 B (stride 328: rows offset 4 banks)
    const int tid = threadIdx.x;
    const int mt = blockIdx.x >> 1, nh = blockIdx.x & 1;

    // stage A: 64 rows x 320 cols (zeros past 300)
#pragma unroll
    for (int it = 0; it < 5; it++) {
        int x = it * 256 + tid;            // 0..1279
        int row = x / 20, seg = x - row * 20;
        int gr = mt * 64 + row;
        const float* ar = emb + (size_t)(gr < Vn ? gr : Vn - 1) * En;
        int c0 = seg * 16;
        union { __bf16 h[16]; bf16x8 v[2]; } pk;
#pragma unroll
        for (int g = 0; g < 4; g++) {
            int c = c0 + g * 4;
            if (c + 4 <= En) {
                float4 f = *(const float4*)(ar + c);
                pk.h[g * 4 + 0] = (__bf16)f.x; pk.h[g * 4 + 1] = (__bf16)f.y;
                pk.h[g * 4 + 2] = (__bf16)f.z; pk.h[g * 4 + 3] = (__bf16)f.w;
            } else {
                pk.h[g * 4 + 0] = (__bf16)0.f; pk.h[g * 4 + 1] = (__bf16)0.f;
                pk.h[g * 4 + 2] = (__bf16)0.f; pk.h[g * 4 + 3] = (__bf16)0.f;
            }
        }
        *(bf16x8*)&a_sh[row][c0] = pk.v[0];
        *(bf16x8*)&a_sh[row][c0 + 8] = pk.v[1];
    }
    __syncthreads();

    const int wv = tid >> 6, l = tid & 63;
    const int c16 = l & 15, quad = l >> 4;
    f32x4 acc[14];
#pragma unroll
    for (int i = 0; i < 14; i++) acc[i] = (f32x4){0.f, 0.f, 0.f, 0.f};

    uint4 bcur[14];
#pragma unroll
    for (int ns = 0; ns < 14; ns++) bcur[ns] = wfragB[((0 * 28 + nh * 14 + ns) << 6) + l];

    for (int kc = 0; kc < 10; kc++) {
        uint4 bnxt[14];
        if (kc < 9) {
#pragma unroll
            for (int ns = 0; ns < 14; ns++) bnxt[ns] = wfragB[(((kc + 1) * 28 + nh * 14 + ns) << 6) + l];
        }
        bf16x8 af = *(const bf16x8*)&a_sh[wv * 16 + c16][kc * 32 + quad * 8];
#pragma unroll
        for (int ns = 0; ns < 14; ns++)
            acc[ns] = __builtin_amdgcn_mfma_f32_16x16x32_bf16(af, __builtin_bit_cast(bf16x8, bcur[ns]), acc[ns], 0, 0, 0);
        if (kc < 9) {
#pragma unroll
            for (int ns = 0; ns < 14; ns++) bcur[ns] = bnxt[ns];
        }
    }
    // epilogue: C/D row = quad*4+r, col = c16
#pragma unroll
    for (int ns = 0; ns < 14; ns++) {
        int n = (nh * 14 + ns) * 16 + c16;
        int q = n & 3, u = n >> 2;
        if (u < Hn) {
            int j = q * Hn + u;
            float bias = b_ih[j] + b_hh[j];
#pragma unroll
            for (int r = 0; r < 4; r++) {
                int m = mt * 64 + wv * 16 + quad * 4 + r;
                if (m < Vn) table[(size_t)m * NPn + n] = (_Float16)(acc[ns][r] + bias);
            }
        }
    }
}

// -------- K2: label_vec = emb[lid] @ ll_W^T + ll_b (2-way K split) -----------
__global__ void k_label(const int* __restrict__ lwid, const float* __restrict__ emb,
                        const float* __restrict__ llwt, const float* __restrict__ llb,
                        float* __restrict__ lv) {
    __shared__ float er[En];
    __shared__ float part[Hn];
    int b = blockIdx.x;
    int lid = lwid[b];
    for (int k = threadIdx.x; k < En; k += 256) er[k] = emb[(size_t)lid * En + k];
    __syncthreads();
    int h = threadIdx.x & 127, half = threadIdx.x >> 7;
    float acc = 0.f;
    if (h < Hn) {
        int k0 = half * 150, k1 = k0 + 150;
        for (int k = k0; k < k1; k++) acc += er[k] * llwt[k * Hn + h];
        if (half == 1) part[h] = acc;
    }
    __syncthreads();
    if (h < Hn && half == 0) lv[(size_t)b * Hn + h] = acc + part[h] + llb[h];
}

// -------- K3: fused LSTM, 2 batch/block, MFMA f16, ONE barrier/step ----------
// Wave w owns u in [28w, 28w+28) x mb in {0,1} (lane = 2*u_loc + mb).
// KEY FIX this rev: W_hh fragments (bfr[7][4] = 112 VGPRs) are PINNED into
// registers via empty asm "+v" after the preload. Prior revs reported
// VGPR_Count=96 < 112 -> the compiler was RE-FETCHING all 28 W frags from
// global memory every timestep (28 buffer_loads + ~150 VALU addr instrs per
// wave per step = the dominant issue load). The opaque asm output cannot be
// rematerialized from memory, guaranteeing register residency.
__global__ __launch_bounds__(256, 2) void k_lstm(
    const int* __restrict__ word_id, const int* __restrict__ sen_len,
    const _Float16* __restrict__ table, const uint4* __restrict__ wfrag,
    const float* __restrict__ lv, const float* __restrict__ linW,
    const float* __restrict__ linb, _Float16* __restrict__ oh16,
    float* __restrict__ per_neg, float* __restrict__ d_out) {
    __shared__ float    gbufs[4][280];     // per wave [2 mb][140] stride-5
    __shared__ _Float16 h_cur[2][2][136];  // [parity][mb][136], cols>=100 zero
    __shared__ float    spw[2][Tn][16];    // per-(wave,row) score partials
    __shared__ int      widc[2][Tn];
    __shared__ float    pos_sh[2][Hn];
    __shared__ float    lasth_sh[2][Hn];
    __shared__ float    tk_val[2][4];
    __shared__ int      tk_idx[2][4];

    const int tid = threadIdx.x;
    const int w = tid >> 6, l = tid & 63;
    const int c16 = l & 15, quad = l >> 4;
    const int b0 = blockIdx.x * 2;

    // init
    for (int i = tid; i < 272; i += 256) ((uint32_t*)h_cur)[i] = 0u;  // both parities + pads
    { int imb = tid >> 7, it = tid & 127; widc[imb][it] = word_id[(b0 + imb) * Tn + it]; }

    // persistent W_hh B-fragments — loaded once, then PINNED in VGPRs
    half8 bfr[7][4];
#pragma unroll
    for (int n7 = 0; n7 < 7; n7++)
#pragma unroll
        for (int kc = 0; kc < 4; kc++)
            bfr[n7][kc] = __builtin_bit_cast(half8, wfrag[((w * 7 + n7) * 4 + kc) * 64 + l]);
#pragma unroll
    for (int n7 = 0; n7 < 7; n7++)
#pragma unroll
        for (int kc = 0; kc < 4; kc++)
            asm volatile("" : "+v"(bfr[n7][kc]));   // opaque: forces register residency

    // lane work identity
    const int u_loc = l >> 1, mb = l & 1;
    const int u = w * 28 + u_loc;
    const bool act = (l < 56) && (u < Hn);
    const int myslen = act ? sen_len[b0 + mb] : 0;
    const float lt_reg = act ? lv[(size_t)(b0 + mb) * Hn + u] : 0.f;
    float* gb = &gbufs[w][0];

    __syncthreads();

    uint2 xq = {0, 0}, xq1 = {0, 0};
    if (act) {
        xq  = *(const uint2*)(table + (size_t)widc[mb][0] * NPn + u * 4);
        xq1 = *(const uint2*)(table + (size_t)widc[mb][1] * NPn + u * 4);
    }

    float c_reg = 0.f, sumh = 0.f, lasth = 0.f;
    float p_carry = 0.f;                    // score partial of step t-1
    _Float16* ohb_w = oh16 + (size_t)(b0 + mb) * Tn * Hn;

    for (int t = 0; t < Tn; t++) {
        // ---- MFMA: gates = h . W_hh^T (A from parity t&1)
        const _Float16* hp = &h_cur[t & 1][0][0];
        f32x4 acc[7];
#pragma unroll
        for (int n7 = 0; n7 < 7; n7++) acc[n7] = (f32x4){0.f, 0.f, 0.f, 0.f};
#pragma unroll
        for (int kc = 0; kc < 4; kc++) {
            half8 af = *(const half8*)(hp + (c16 & 1) * 136 + kc * 32 + quad * 8);
#pragma unroll
            for (int n7 = 0; n7 < 7; n7++)
                acc[n7] = __builtin_amdgcn_mfma_f32_16x16x32_f16(af, bfr[n7][kc], acc[n7], 0, 0, 0);
        }
        // ---- deferred score reduce for step t-1 (VALU DPP; overlaps MFMA)
        {
            float pr = p_carry;
            DPP_ADD_SHL(pr, 2);
            DPP_ADD_SHL(pr, 4);
            DPP_ADD_SHL(pr, 8);
            // lanes with (l&15)<2 hold row partials (parity = mb)
            if ((l & 15) < 2 && t > 0) spw[l & 1][t - 1][w * 4 + quad] = pr;
        }
        // ---- wave-local gate stage (C rows 0,1 live in quad 0)
        if (l < 16) {
#pragma unroll
            for (int n7 = 0; n7 < 7; n7++) {
                int nl = n7 * 16 + l;
                int adr = (nl >> 2) * 5 + (nl & 3);
                gb[adr] = acc[n7][0];
                gb[140 + adr] = acc[n7][1];
            }
        }
        // wave-synchronous: lgkmcnt ordering within wave, no barrier
        float p = 0.f;
        if (act) {
            int base = mb * 140 + u_loc * 5;
            half2v x01 = __builtin_bit_cast(half2v, xq.x);
            half2v x23 = __builtin_bit_cast(half2v, xq.y);
            float gi = gb[base] + (float)x01.x;
            float gf = gb[base + 1] + (float)x01.y;
            float gg = gb[base + 2] + (float)x23.x;
            float go = gb[base + 3] + (float)x23.y;
            float c = sigf(gf) * c_reg + sigf(gi) * tanhfast(gg);
            c_reg = c;
            float hh = sigf(go) * tanhfast(c);
            h_cur[(t + 1) & 1][mb][u] = (_Float16)hh;
            ohb_w[t * Hn + u] = (_Float16)hh;
            if (t < myslen) sumh += hh;
            if (t == myslen - 1) lasth = hh;
            p = hh * lt_reg;
            int tn2 = (t + 2 < Tn) ? t + 2 : Tn - 1;
            xq = xq1;
            xq1 = *(const uint2*)(table + (size_t)widc[mb][tn2] * NPn + u * 4);
        }
        p_carry = p;
        BAR_LDS();  // h(t+1) + spw visible to all waves; vmcnt stays in flight
    }
    // final deferred reduce for t = Tn-1
    {
        float pr = p_carry;
        DPP_ADD_SHL(pr, 2);
        DPP_ADD_SHL(pr, 4);
        DPP_ADD_SHL(pr, 8);
        if ((l & 15) < 2) spw[l & 1][Tn - 1][w * 4 + quad] = pr;
    }
    __syncthreads();  // spw complete; drains vmcnt (oh16 stores) before re-read
    // ---- top-4: wave 0 -> mb 0, wave 1 -> mb 1; tie-break smaller index
    if (w < 2) {
        int kmb = w, lane = l;
        int sl = sen_len[b0 + kmb];
        const float* s16a = &spw[kmb][lane][0];
        const float* s16b = &spw[kmb][lane + 64][0];
        float4 a0 = *(const float4*)(s16a + 0), a1 = *(const float4*)(s16a + 4);
        float4 a2 = *(const float4*)(s16a + 8), a3 = *(const float4*)(s16a + 12);
        float4 b0v = *(const float4*)(s16b + 0), b1v = *(const float4*)(s16b + 4);
        float4 b2v = *(const float4*)(s16b + 8), b3v = *(const float4*)(s16b + 12);
        float sa = (a0.x + a0.y + a0.z + a0.w) + (a1.x + a1.y + a1.z + a1.w)
                 + (a2.x + a2.y + a2.z + a2.w) + (a3.x + a3.y + a3.z + a3.w);
        float sb = (b0v.x + b0v.y + b0v.z + b0v.w) + (b1v.x + b1v.y + b1v.z + b1v.w)
                 + (b2v.x + b2v.y + b2v.z + b2v.w) + (b3v.x + b3v.y + b3v.z + b3v.w);
        float s0 = (lane < sl) ? sa : -1e30f;
        float s1 = (lane + 64 < sl) ? sb : -1e30f;
        bool tk0 = false, tk1 = false;
#pragma unroll
        for (int p4 = 0; p4 < 4; p4++) {
            float v = tk0 ? -1e30f : s0;
            int ix = lane;
            float v1 = tk1 ? -1e30f : s1;
            if (v1 > v) { v = v1; ix = lane + 64; }
            for (int off = 32; off; off >>= 1) {
                float ov = __shfl_down(v, off, 64);
                int oi = __shfl_down(ix, off, 64);
                if (ov > v || (ov == v && oi < ix)) { v = ov; ix = oi; }
            }
            v = __shfl(v, 0, 64);
            ix = __shfl(ix, 0, 64);
            if (lane == 0) { tk_val[kmb][p4] = v; tk_idx[kmb][p4] = ix; }
            if (ix == lane) tk0 = true;
            if (ix == lane + 64) tk1 = true;
        }
    }
    __syncthreads();
    // ---- pos / per_neg / lasth (lane ownership)
    if (act) {
        float pos = 0.f, nsum = sumh;
#pragma unroll
        for (int p4 = 0; p4 < 4; p4++) {
            int ix = tk_idx[mb][p4];
            float r = (float)ohb_w[ix * Hn + u];
            pos += tk_val[mb][p4] * r;
            nsum -= r;
        }
        pos_sh[mb][u] = pos;
        lasth_sh[mb][u] = lasth;
        per_neg[(size_t)(b0 + mb) * Hn + u] = nsum;
    }
    __syncthreads();
    // ---- projections: out_f = lin(lasth), l_rep = lin(pos)
    if (tid < 24) {
        int which = tid / 12, r = tid - which * 12;
        int pmb = r / 6, o = r - pmb * 6;
        const float* src = which ? &pos_sh[pmb][0] : &lasth_sh[pmb][0];
        float acc2 = linb[o];
        for (int uu = 0; uu < Hn; uu++) acc2 += src[uu] * linW[o * Hn + uu];
        d_out[(which ? (Bn * 6) : 0) + (b0 + pmb) * 6 + o] = acc2;
    }
}

// -------- K4: batch cumsum of per_neg (wave-shuffle scan, 2 barriers) --------
__global__ __launch_bounds__(1024) void k_scan(const float* __restrict__ pn, float* __restrict__ neg) {
    __shared__ float wsum[16];
    __shared__ float wpre[16];
    int u = blockIdx.x, t = threadIdx.x;
    int lane = t & 63, wv = t >> 6;
    float v = pn[(size_t)t * Hn + u];
#pragma unroll
    for (int off = 1; off < 64; off <<= 1) {
        float o = __shfl_up(v, off, 64);
        if (lane >= off) v += o;
    }
    if (lane == 63) wsum[wv] = v;
    __syncthreads();
    if (t < 16) {
        float s = wsum[t];
#pragma unroll
        for (int off = 1; off < 16; off <<= 1) {
            float o = __shfl_up(s, off, 64);
            if (t >= off) s += o;
        }
        wpre[t] = s;
    }
    __syncthreads();
    float pre = wv ? wpre[wv - 1] : 0.f;
    neg[(size_t)t * Hn + u] = v + pre;
}

// -------- K5: r_rep = neg @ lin_W^T + lin_b ----------------------------------
__global__ void k_rrep(const float* __restrict__ neg, const float* __restrict__ linW,
                       const float* __restrict__ linb, float* __restrict__ d_out) {
    int gid = blockIdx.x * 256 + threadIdx.x;
    if (gid < Bn * 6) {
        int b = gid / 6, o = gid - b * 6;
        float acc = linb[o];
        for (int u = 0; u < Hn; u++) acc += neg[(size_t)b * Hn + u] * linW[o * Hn + u];
        d_out[2 * Bn * 6 + gid] = acc;
    }
}

extern "C" void kernel_launch(void* const* d_in, const int* in_sizes, int n_in,
                              void* d_out, int out_size, void* d_ws, size_t ws_size,
                              hipStream_t stream) {
    const int*   word_id = (const int*)d_in[0];
    const int*   sen_len = (const int*)d_in[1];
    const int*   lwid    = (const int*)d_in[2];
    const float* emb     = (const float*)d_in[3];
    const float* W_ih    = (const float*)d_in[4];
    const float* W_hh    = (const float*)d_in[5];
    const float* b_ih    = (const float*)d_in[6];
    const float* b_hh    = (const float*)d_in[7];
    const float* linW    = (const float*)d_in[8];
    const float* linb    = (const float*)d_in[9];
    const float* llW     = (const float*)d_in[10];
    const float* llb     = (const float*)d_in[11];

    char* ws = (char*)d_ws;
    _Float16* table  = (_Float16*)(ws + OFF_TABLE);
    _Float16* oh16   = (_Float16*)(ws + OFF_OH16);
    uint4*    wfrag  = (uint4*)(ws + OFF_WFRAG);
    uint4*    wfragB = (uint4*)(ws + OFF_WFRAGB);
    float*    llwt   = (float*)(ws + OFF_LLWT);
    float*    lvp    = (float*)(ws + OFF_LV);
    float*    pn     = (float*)(ws + OFF_PN);
    float*    neg    = (float*)(ws + OFF_NEG);
    float*    outp   = (float*)d_out;

    k_prep<<<118, 256, 0, stream>>>(W_ih, W_hh, llW, wfrag, wfragB, llwt);
    k_table<<<(MPn / 64) * 2, 256, 0, stream>>>(emb, wfragB, b_ih, b_hh, table);
    k_label<<<Bn, 256, 0, stream>>>(lwid, emb, llwt, llb, lvp);
    k_lstm<<<Bn / 2, 256, 0, stream>>>(word_id, sen_len, table, wfrag, lvp, linW, linb, oh16, pn, outp);
    k_scan<<<Hn, 1024, 0, stream>>>(pn, neg);
    k_rrep<<<(Bn * 6 + 255) / 256, 256, 0, stream>>>(neg, linW, linb, outp);
}